// Round 10
// baseline (115.114 us; speedup 1.0000x reference)
//
#include <hip/hip_runtime.h>
#include <math.h>

#define D 256
#define K2 512          // 2*D
#define BATCH 1024      // n2
#define N1 11264        // n1 = B*(1+10)
#define S0 25
#define S1 10

typedef __bf16 bf16x8 __attribute__((ext_vector_type(8)));
typedef __bf16 bf16x4 __attribute__((ext_vector_type(4)));
typedef float  f32x4  __attribute__((ext_vector_type(4)));

// ---------------------------------------------------------------------------
// fused_layer0 (RB=16): per block of 16 output rows:
//   phase 1 (gather): wave w gathers rows [4w, 4w+4): self + mean of 25
//     neighbor fp32 rows -> bf16 -> swizzled full-K LDS A-tile [16][512].
//   phase 2 (GEMM): 8 k-tiles of 64; B staged from fp32 W0 with inline bf16
//     cvt (reg-prefetched); 16x16x32 bf16 MFMA; A resident in LDS.
//   epilogue: bias + relu + row-l2norm -> h1b (bf16).
// WHY RB=16 (R9 lesson): RB=32 needed 66.5KB LDS (>64KB) -> occupancy was
// 1 block/CU (12.4%) -> gather ran at 4.3 TB/s with no cross-block overlap.
// RB=16 -> 48.7KB -> 3 blocks/CU by LDS (VGPR 104 caps ~16 waves/CU), 704
// blocks -> gather gets prep-level TLP (~12 waves/CU) AND overlaps GEMM of
// neighboring blocks. Serial row-waits per wave halve (4 vs 8).
// Fragment mapping (m89): A/B lane l: row/col=l&15, k=(l>>4)*8+i.
// C/D: col=l&15, row=(l>>4)*4+reg.
// ---------------------------------------------------------------------------
__global__ __launch_bounds__(256, 2) void fused_layer0(
        const float* __restrict__ feat, const float* __restrict__ W0,
        const float* __restrict__ b0, const int* __restrict__ nodes2,
        const int* __restrict__ neigh2, const int* __restrict__ neigh1,
        __bf16* __restrict__ h1b) {
    __shared__ __bf16 Atile[16 * 512];   // 16KB, swizzled granules of 8 bf16
    __shared__ __bf16 Bs[256 * 64];      // 32KB, tile16 layout
    __shared__ float ssLDS[4][16];
    __shared__ float invLDS[16];

    const int tid = threadIdx.x;
    const int lane = tid & 63;
    const int w = tid >> 6;
    const int rl = lane & 15;
    const int g = lane >> 4;
    const int row0 = blockIdx.x * 16;

    // ---- B prologue loads (k0 = 0), fp32, 2 float4 per slot ----
    float4 rb0[8], rb1[8];
#pragma unroll
    for (int s = 0; s < 8; ++s) {
        int i = tid + s * 256;
        int cg = i >> 7, kc = (i >> 4) & 7, lo = i & 15;
        const float* p = W0 + (size_t)(cg * 16 + lo) * K2 + kc * 8;
        rb0[s] = *(const float4*)p;
        rb1[s] = *(const float4*)(p + 4);
    }

    // ---- gather phase: wave w handles rows [4w, 4w+4) ----
#pragma unroll 1
    for (int r = w * 4; r < w * 4 + 4; ++r) {
        const int gr = row0 + r;
        const int self_idx = (gr < BATCH) ? nodes2[gr] : neigh2[gr - BATCH];
        const int* nb = neigh1 + (size_t)gr * S0;
        int idx[S0];
#pragma unroll
        for (int j = 0; j < S0; ++j) idx[j] = nb[j];
        float4 sv = ((const float4*)(feat + (size_t)self_idx * D))[lane];
        float4 v[S0];
#pragma unroll
        for (int j = 0; j < S0; ++j)
            v[j] = ((const float4*)(feat + (size_t)idx[j] * D))[lane];
        __builtin_amdgcn_sched_barrier(0);
        float4 acc = make_float4(0.f, 0.f, 0.f, 0.f);
#pragma unroll
        for (int j = 0; j < S0; ++j) {
            acc.x += v[j].x; acc.y += v[j].y; acc.z += v[j].z; acc.w += v[j].w;
        }
        const float s25 = 1.0f / 25.0f;
        bf16x4 svb = { (__bf16)sv.x, (__bf16)sv.y, (__bf16)sv.z, (__bf16)sv.w };
        bf16x4 avb = { (__bf16)(acc.x * s25), (__bf16)(acc.y * s25),
                       (__bf16)(acc.z * s25), (__bf16)(acc.w * s25) };
        // self dims [4l,4l+4) -> granule l>>1 (half l&1); agg dims +256 -> +32 granules
        const int sw = r & 7;
        const int gs = (lane >> 1) ^ sw;
        const int ga = (32 + (lane >> 1)) ^ sw;
        *(bf16x4*)(Atile + (size_t)r * 512 + gs * 8 + (lane & 1) * 4) = svb;
        *(bf16x4*)(Atile + (size_t)r * 512 + ga * 8 + (lane & 1) * 4) = avb;
    }
    __syncthreads();

    // ---- GEMM phase: wave w owns cols [64w, 64w+64), all 16 rows ----
    f32x4 acc[4];
#pragma unroll
    for (int nf = 0; nf < 4; ++nf) acc[nf] = (f32x4){0.f, 0.f, 0.f, 0.f};

    for (int k0 = 0; k0 < K2; k0 += 64) {
        // write Bs from prefetched fp32 regs with inline cvt (linear in tid)
#pragma unroll
        for (int s = 0; s < 8; ++s) {
            int i = tid + s * 256;
            bf16x8 bv;
            bv[0] = (__bf16)rb0[s].x; bv[1] = (__bf16)rb0[s].y;
            bv[2] = (__bf16)rb0[s].z; bv[3] = (__bf16)rb0[s].w;
            bv[4] = (__bf16)rb1[s].x; bv[5] = (__bf16)rb1[s].y;
            bv[6] = (__bf16)rb1[s].z; bv[7] = (__bf16)rb1[s].w;
            *(bf16x8*)(Bs + (size_t)i * 8) = bv;
        }
        __syncthreads();
        if (k0 + 64 < K2) {
#pragma unroll
            for (int s = 0; s < 8; ++s) {
                int i = tid + s * 256;
                int cg = i >> 7, kc = (i >> 4) & 7, lo = i & 15;
                const float* p = W0 + (size_t)(cg * 16 + lo) * K2 + (k0 + 64) + kc * 8;
                rb0[s] = *(const float4*)p;
                rb1[s] = *(const float4*)(p + 4);
            }
        }
#pragma unroll
        for (int kf = 0; kf < 2; ++kf) {
            const int kc = kf * 4 + g;
            const int gA = (k0 >> 3) + kc;  // granule index within a row
            bf16x8 af = *(const bf16x8*)(Atile + (size_t)rl * 512 +
                                         (size_t)(gA ^ (rl & 7)) * 8);
            bf16x8 bfr[4];
#pragma unroll
            for (int nf = 0; nf < 4; ++nf)
                bfr[nf] = *(const bf16x8*)(Bs + ((size_t)((w * 4 + nf) * 8 + kc) * 16 + rl) * 8);
#pragma unroll
            for (int nf = 0; nf < 4; ++nf)
                acc[nf] = __builtin_amdgcn_mfma_f32_16x16x32_bf16(af, bfr[nf], acc[nf], 0, 0, 0);
        }
        __syncthreads();
    }

    // ---- epilogue: bias + relu + row L2 norm + store bf16 ----
    float bv[4];
#pragma unroll
    for (int nf = 0; nf < 4; ++nf) bv[nf] = b0[w * 64 + nf * 16 + rl];

    float ss0 = 0.f, ss1 = 0.f, ss2 = 0.f, ss3 = 0.f;
#pragma unroll
    for (int nf = 0; nf < 4; ++nf) {
        float v0 = fmaxf(acc[nf][0] + bv[nf], 0.f);
        float v1 = fmaxf(acc[nf][1] + bv[nf], 0.f);
        float v2 = fmaxf(acc[nf][2] + bv[nf], 0.f);
        float v3 = fmaxf(acc[nf][3] + bv[nf], 0.f);
        acc[nf][0] = v0; acc[nf][1] = v1;
        acc[nf][2] = v2; acc[nf][3] = v3;
        ss0 += v0 * v0; ss1 += v1 * v1; ss2 += v2 * v2; ss3 += v3 * v3;
    }
#pragma unroll
    for (int m = 1; m < 16; m <<= 1) {
        ss0 += __shfl_xor(ss0, m);
        ss1 += __shfl_xor(ss1, m);
        ss2 += __shfl_xor(ss2, m);
        ss3 += __shfl_xor(ss3, m);
    }
    float ssv = (rl == 0) ? ss0 : (rl == 1) ? ss1 : (rl == 2) ? ss2 : ss3;
    if (rl < 4) ssLDS[w][g * 4 + rl] = ssv;
    __syncthreads();
    if (tid < 16) {
        float t = ssLDS[0][tid] + ssLDS[1][tid] + ssLDS[2][tid] + ssLDS[3][tid];
        invLDS[tid] = (t > 0.f) ? rsqrtf(t) : 1.0f;
    }
    __syncthreads();
#pragma unroll
    for (int j = 0; j < 4; ++j) {
        const int row = g * 4 + j;
        const float inv = invLDS[row];
#pragma unroll
        for (int nf = 0; nf < 4; ++nf)
            h1b[(size_t)(row0 + row) * D + w * 64 + nf * 16 + rl] =
                (__bf16)(acc[nf][j] * inv);
    }
}

// ---------------------------------------------------------------------------
// fused_layer1 (unchanged, ~9-10us): Out[1024][256] = l2norm(relu(X1 @ W1^T
// + b1)), X1 row i = [h1[i] | mean_j h1[1024+i*10+j]] built on the fly in
// A-staging (h1 bf16). B staged from fp32 W1 with inline cvt + reg prefetch.
// ---------------------------------------------------------------------------
__global__ __launch_bounds__(256, 2) void fused_layer1(
        const __bf16* __restrict__ h1, const float* __restrict__ W1,
        const float* __restrict__ b1, float* __restrict__ Out) {
    constexpr int RB = 32;
    __shared__ __bf16 As[RB * 64];
    __shared__ __bf16 Bs[256 * 64];
    __shared__ float ssLDS[4][RB];
    __shared__ float invLDS[RB];

    const int tid = threadIdx.x;
    const int row0 = blockIdx.x * RB;
    const int lane = tid & 63;
    const int w = tid >> 6;
    const int rl = lane & 15;
    const int g = lane >> 4;
    const int rg = tid >> 7, kc8 = (tid >> 4) & 7, lo = tid & 15;
    const int grow = row0 + rg * 16 + lo;

    // B prologue (k0 = 0)
    float4 rb0[8], rb1[8];
#pragma unroll
    for (int s = 0; s < 8; ++s) {
        int i = tid + s * 256;
        int cg = i >> 7, kc = (i >> 4) & 7, blo = i & 15;
        const float* p = W1 + (size_t)(cg * 16 + blo) * K2 + kc * 8;
        rb0[s] = *(const float4*)p;
        rb1[s] = *(const float4*)(p + 4);
    }

    f32x4 acc[2][4];
#pragma unroll
    for (int rf = 0; rf < 2; ++rf)
#pragma unroll
        for (int nf = 0; nf < 4; ++nf) acc[rf][nf] = (f32x4){0.f, 0.f, 0.f, 0.f};

    for (int k0 = 0; k0 < K2; k0 += 64) {
        // fused A-staging (build X1 tile on the fly)
        bf16x8 av;
        if (k0 < 256) {
            av = *(const bf16x8*)(h1 + (size_t)grow * D + k0 + kc8 * 8);
        } else {
            float f[8];
#pragma unroll
            for (int e = 0; e < 8; ++e) f[e] = 0.f;
            const __bf16* base = h1 + (size_t)(BATCH + grow * S1) * D + (k0 - 256) + kc8 * 8;
#pragma unroll
            for (int j = 0; j < S1; ++j) {
                bf16x8 vv = *(const bf16x8*)(base + (size_t)j * D);
#pragma unroll
                for (int e = 0; e < 8; ++e) f[e] += (float)vv[e];
            }
#pragma unroll
            for (int e = 0; e < 8; ++e) av[e] = (__bf16)(f[e] * 0.1f);
        }
        *(bf16x8*)(As + (size_t)tid * 8) = av;
        // B-staging from prefetched regs with cvt
#pragma unroll
        for (int s = 0; s < 8; ++s) {
            int i = tid + s * 256;
            bf16x8 bb;
            bb[0] = (__bf16)rb0[s].x; bb[1] = (__bf16)rb0[s].y;
            bb[2] = (__bf16)rb0[s].z; bb[3] = (__bf16)rb0[s].w;
            bb[4] = (__bf16)rb1[s].x; bb[5] = (__bf16)rb1[s].y;
            bb[6] = (__bf16)rb1[s].z; bb[7] = (__bf16)rb1[s].w;
            *(bf16x8*)(Bs + (size_t)i * 8) = bb;
        }
        __syncthreads();
        if (k0 + 64 < K2) {
#pragma unroll
            for (int s = 0; s < 8; ++s) {
                int i = tid + s * 256;
                int cg = i >> 7, kc = (i >> 4) & 7, blo = i & 15;
                const float* p = W1 + (size_t)(cg * 16 + blo) * K2 + (k0 + 64) + kc * 8;
                rb0[s] = *(const float4*)p;
                rb1[s] = *(const float4*)(p + 4);
            }
        }
#pragma unroll
        for (int kf = 0; kf < 2; ++kf) {
            const int kc = kf * 4 + g;
            bf16x8 af[2], bfr[4];
#pragma unroll
            for (int rf = 0; rf < 2; ++rf)
                af[rf] = *(const bf16x8*)(As + ((size_t)(rf * 8 + kc) * 16 + rl) * 8);
#pragma unroll
            for (int nf = 0; nf < 4; ++nf)
                bfr[nf] = *(const bf16x8*)(Bs + ((size_t)((w * 4 + nf) * 8 + kc) * 16 + rl) * 8);
#pragma unroll
            for (int rf = 0; rf < 2; ++rf)
#pragma unroll
                for (int nf = 0; nf < 4; ++nf)
                    acc[rf][nf] = __builtin_amdgcn_mfma_f32_16x16x32_bf16(
                        af[rf], bfr[nf], acc[rf][nf], 0, 0, 0);
        }
        __syncthreads();
    }

    float bv[4];
#pragma unroll
    for (int nf = 0; nf < 4; ++nf) bv[nf] = b1[w * 64 + nf * 16 + rl];

#pragma unroll
    for (int rf = 0; rf < 2; ++rf) {
        float ss0 = 0.f, ss1 = 0.f, ss2 = 0.f, ss3 = 0.f;
#pragma unroll
        for (int nf = 0; nf < 4; ++nf) {
            float v0 = fmaxf(acc[rf][nf][0] + bv[nf], 0.f);
            float v1 = fmaxf(acc[rf][nf][1] + bv[nf], 0.f);
            float v2 = fmaxf(acc[rf][nf][2] + bv[nf], 0.f);
            float v3 = fmaxf(acc[rf][nf][3] + bv[nf], 0.f);
            acc[rf][nf][0] = v0; acc[rf][nf][1] = v1;
            acc[rf][nf][2] = v2; acc[rf][nf][3] = v3;
            ss0 += v0 * v0; ss1 += v1 * v1; ss2 += v2 * v2; ss3 += v3 * v3;
        }
#pragma unroll
        for (int m = 1; m < 16; m <<= 1) {
            ss0 += __shfl_xor(ss0, m);
            ss1 += __shfl_xor(ss1, m);
            ss2 += __shfl_xor(ss2, m);
            ss3 += __shfl_xor(ss3, m);
        }
        float ssv = (rl == 0) ? ss0 : (rl == 1) ? ss1 : (rl == 2) ? ss2 : ss3;
        if (rl < 4) ssLDS[w][rf * 16 + g * 4 + rl] = ssv;
    }
    __syncthreads();
    if (tid < RB) {
        float t = ssLDS[0][tid] + ssLDS[1][tid] + ssLDS[2][tid] + ssLDS[3][tid];
        invLDS[tid] = (t > 0.f) ? rsqrtf(t) : 1.0f;
    }
    __syncthreads();
#pragma unroll
    for (int rf = 0; rf < 2; ++rf)
#pragma unroll
        for (int j = 0; j < 4; ++j) {
            const int row = rf * 16 + g * 4 + j;
            const float inv = invLDS[row];
#pragma unroll
            for (int nf = 0; nf < 4; ++nf)
                Out[(size_t)(row0 + row) * D + w * 64 + nf * 16 + rl] = acc[rf][nf][j] * inv;
        }
}

// ---------------------------------------------------------------------------
extern "C" void kernel_launch(void* const* d_in, const int* in_sizes, int n_in,
                              void* d_out, int out_size, void* d_ws, size_t ws_size,
                              hipStream_t stream) {
    const float* features = (const float*)d_in[0];
    const float* W0       = (const float*)d_in[1];
    const float* b0       = (const float*)d_in[2];
    const float* W1       = (const float*)d_in[3];
    const float* b1       = (const float*)d_in[4];
    const int*   nodes2   = (const int*)d_in[5];
    const int*   neigh2   = (const int*)d_in[6];
    const int*   neigh1   = (const int*)d_in[7];
    float* out = (float*)d_out;

    __bf16* h1b = (__bf16*)d_ws;   // 11264*256*2 = 5.75 MB

    fused_layer0<<<N1 / 16, 256, 0, stream>>>(features, W0, b0, nodes2, neigh2,
                                              neigh1, h1b);
    fused_layer1<<<BATCH / 32, 256, 0, stream>>>(h1b, W1, b1, out);
}

// Round 11
// 102.528 us; speedup vs baseline: 1.1228x; 1.1228x over previous
//
#include <hip/hip_runtime.h>
#include <math.h>

#define D 256
#define K2 512          // 2*D
#define BATCH 1024      // n2
#define N1 11264        // n1 = B*(1+10)
#define S0 25
#define S1 10

typedef __bf16 bf16x8 __attribute__((ext_vector_type(8)));
typedef __bf16 bf16x4 __attribute__((ext_vector_type(4)));
typedef float  f32x4  __attribute__((ext_vector_type(4)));

// ---------------------------------------------------------------------------
// fused_layer0 (RB=32, BK=32): per block of 32 output rows:
//   phase 1 (gather): wave w gathers rows [8w, 8w+8): self + mean of 25
//     neighbor fp32 rows -> bf16 -> swizzled full-K LDS A-tile [32][512].
//   phase 2 (GEMM): 16 k-tiles of 32; B staged from fp32 W0 with inline bf16
//     cvt (reg-prefetched); 16x16x32 bf16 MFMA; A resident in LDS.
//   epilogue: bias + relu + row-l2norm -> h1b (bf16).
// WHY BK=32 (R10 lesson): R8 (RB=32,BK=64) used 66.5KB LDS -> 2 blocks/CU
// theoretical, 1 measured -> gather at 8 waves/CU = 1.73 TB/s. R10's RB=16
// doubled the grid and W0 traffic -> net loss. Here: SAME grid (352), SAME
// W0 traffic (180MB), but LDS 48.7KB -> 3 blocks/CU -> gather TLP at prep's
// level (12 waves/CU gave 2.66 TB/s in R3).
// Fragment mapping (m89): A/B lane l: row/col=l&15, k=(l>>4)*8+i.
// C/D: col=l&15, row=(l>>4)*4+reg.
// ---------------------------------------------------------------------------
__global__ __launch_bounds__(256, 3) void fused_layer0(
        const float* __restrict__ feat, const float* __restrict__ W0,
        const float* __restrict__ b0, const int* __restrict__ nodes2,
        const int* __restrict__ neigh2, const int* __restrict__ neigh1,
        __bf16* __restrict__ h1b) {
    __shared__ __bf16 Atile[32 * 512];   // 32KB, swizzled granules of 8 bf16
    __shared__ __bf16 Bs[256 * 32];      // 16KB: [cg 0..15][kc 0..3][lo 0..15]
    __shared__ float ssLDS[4][32];
    __shared__ float invLDS[32];

    const int tid = threadIdx.x;
    const int lane = tid & 63;
    const int w = tid >> 6;
    const int rl = lane & 15;
    const int g = lane >> 4;
    const int row0 = blockIdx.x * 32;

    // ---- B prologue loads (k0 = 0), fp32, 4 slots x 32B per thread ----
    float4 rb0[4], rb1[4];
#pragma unroll
    for (int s = 0; s < 4; ++s) {
        int i = tid + s * 256;
        int cg = i >> 6, kc = (i >> 4) & 3, lo = i & 15;
        const float* p = W0 + (size_t)(cg * 16 + lo) * K2 + kc * 8;
        rb0[s] = *(const float4*)p;
        rb1[s] = *(const float4*)(p + 4);
    }

    // ---- gather phase: wave w handles rows [8w, 8w+8) ----
#pragma unroll 1
    for (int r = w * 8; r < w * 8 + 8; ++r) {
        const int gr = row0 + r;
        const int self_idx = (gr < BATCH) ? nodes2[gr] : neigh2[gr - BATCH];
        const int* nb = neigh1 + (size_t)gr * S0;
        int idx[S0];
#pragma unroll
        for (int j = 0; j < S0; ++j) idx[j] = nb[j];
        float4 sv = ((const float4*)(feat + (size_t)self_idx * D))[lane];
        float4 v[S0];
#pragma unroll
        for (int j = 0; j < S0; ++j)
            v[j] = ((const float4*)(feat + (size_t)idx[j] * D))[lane];
        __builtin_amdgcn_sched_barrier(0);
        float4 acc = make_float4(0.f, 0.f, 0.f, 0.f);
#pragma unroll
        for (int j = 0; j < S0; ++j) {
            acc.x += v[j].x; acc.y += v[j].y; acc.z += v[j].z; acc.w += v[j].w;
        }
        const float s25 = 1.0f / 25.0f;
        bf16x4 svb = { (__bf16)sv.x, (__bf16)sv.y, (__bf16)sv.z, (__bf16)sv.w };
        bf16x4 avb = { (__bf16)(acc.x * s25), (__bf16)(acc.y * s25),
                       (__bf16)(acc.z * s25), (__bf16)(acc.w * s25) };
        // self dims [4l,4l+4) -> granule l>>1 (half l&1); agg dims +256 -> +32 granules
        const int sw = r & 7;
        const int gs = (lane >> 1) ^ sw;
        const int ga = (32 + (lane >> 1)) ^ sw;
        *(bf16x4*)(Atile + (size_t)r * 512 + gs * 8 + (lane & 1) * 4) = svb;
        *(bf16x4*)(Atile + (size_t)r * 512 + ga * 8 + (lane & 1) * 4) = avb;
    }
    __syncthreads();

    // ---- GEMM phase: 16 k-tiles of 32 ----
    f32x4 acc[2][4];
#pragma unroll
    for (int rf = 0; rf < 2; ++rf)
#pragma unroll
        for (int nf = 0; nf < 4; ++nf) acc[rf][nf] = (f32x4){0.f, 0.f, 0.f, 0.f};

    for (int k0 = 0; k0 < K2; k0 += 32) {
        // write Bs from prefetched fp32 regs with inline cvt (linear in tid)
#pragma unroll
        for (int s = 0; s < 4; ++s) {
            int i = tid + s * 256;
            bf16x8 bv;
            bv[0] = (__bf16)rb0[s].x; bv[1] = (__bf16)rb0[s].y;
            bv[2] = (__bf16)rb0[s].z; bv[3] = (__bf16)rb0[s].w;
            bv[4] = (__bf16)rb1[s].x; bv[5] = (__bf16)rb1[s].y;
            bv[6] = (__bf16)rb1[s].z; bv[7] = (__bf16)rb1[s].w;
            *(bf16x8*)(Bs + (size_t)i * 8) = bv;
        }
        __syncthreads();
        if (k0 + 32 < K2) {
#pragma unroll
            for (int s = 0; s < 4; ++s) {
                int i = tid + s * 256;
                int cg = i >> 6, kc = (i >> 4) & 3, lo = i & 15;
                const float* p = W0 + (size_t)(cg * 16 + lo) * K2 + (k0 + 32) + kc * 8;
                rb0[s] = *(const float4*)p;
                rb1[s] = *(const float4*)(p + 4);
            }
        }
        {
            const int gA = (k0 >> 3) + g;   // granule index within a row
            bf16x8 af[2], bfr[4];
#pragma unroll
            for (int rf = 0; rf < 2; ++rf) {
                int row = rf * 16 + rl;
                af[rf] = *(const bf16x8*)(Atile + (size_t)row * 512 +
                                          (size_t)(gA ^ (row & 7)) * 8);
            }
#pragma unroll
            for (int nf = 0; nf < 4; ++nf)
                bfr[nf] = *(const bf16x8*)(Bs + ((size_t)((w * 4 + nf) * 4 + g) * 16 + rl) * 8);
#pragma unroll
            for (int rf = 0; rf < 2; ++rf)
#pragma unroll
                for (int nf = 0; nf < 4; ++nf)
                    acc[rf][nf] = __builtin_amdgcn_mfma_f32_16x16x32_bf16(
                        af[rf], bfr[nf], acc[rf][nf], 0, 0, 0);
        }
        __syncthreads();
    }

    // ---- epilogue: bias + relu + row L2 norm + store bf16 ----
    float bv[4];
#pragma unroll
    for (int nf = 0; nf < 4; ++nf) bv[nf] = b0[w * 64 + nf * 16 + rl];

#pragma unroll
    for (int rf = 0; rf < 2; ++rf) {
        float ss0 = 0.f, ss1 = 0.f, ss2 = 0.f, ss3 = 0.f;
#pragma unroll
        for (int nf = 0; nf < 4; ++nf) {
            float v0 = fmaxf(acc[rf][nf][0] + bv[nf], 0.f);
            float v1 = fmaxf(acc[rf][nf][1] + bv[nf], 0.f);
            float v2 = fmaxf(acc[rf][nf][2] + bv[nf], 0.f);
            float v3 = fmaxf(acc[rf][nf][3] + bv[nf], 0.f);
            acc[rf][nf][0] = v0; acc[rf][nf][1] = v1;
            acc[rf][nf][2] = v2; acc[rf][nf][3] = v3;
            ss0 += v0 * v0; ss1 += v1 * v1; ss2 += v2 * v2; ss3 += v3 * v3;
        }
#pragma unroll
        for (int m = 1; m < 16; m <<= 1) {
            ss0 += __shfl_xor(ss0, m);
            ss1 += __shfl_xor(ss1, m);
            ss2 += __shfl_xor(ss2, m);
            ss3 += __shfl_xor(ss3, m);
        }
        float ssv = (rl == 0) ? ss0 : (rl == 1) ? ss1 : (rl == 2) ? ss2 : ss3;
        if (rl < 4) ssLDS[w][rf * 16 + g * 4 + rl] = ssv;
    }
    __syncthreads();
    if (tid < 32) {
        float t = ssLDS[0][tid] + ssLDS[1][tid] + ssLDS[2][tid] + ssLDS[3][tid];
        invLDS[tid] = (t > 0.f) ? rsqrtf(t) : 1.0f;
    }
    __syncthreads();
#pragma unroll
    for (int rf = 0; rf < 2; ++rf)
#pragma unroll
        for (int j = 0; j < 4; ++j) {
            const int row = rf * 16 + g * 4 + j;
            const float inv = invLDS[row];
#pragma unroll
            for (int nf = 0; nf < 4; ++nf)
                h1b[(size_t)(row0 + row) * D + w * 64 + nf * 16 + rl] =
                    (__bf16)(acc[rf][nf][j] * inv);
        }
}

// ---------------------------------------------------------------------------
// fused_layer1 (unchanged, ~9-10us): Out[1024][256] = l2norm(relu(X1 @ W1^T
// + b1)), X1 row i = [h1[i] | mean_j h1[1024+i*10+j]] built on the fly in
// A-staging (h1 bf16). B staged from fp32 W1 with inline cvt + reg prefetch.
// ---------------------------------------------------------------------------
__global__ __launch_bounds__(256, 2) void fused_layer1(
        const __bf16* __restrict__ h1, const float* __restrict__ W1,
        const float* __restrict__ b1, float* __restrict__ Out) {
    constexpr int RB = 32;
    __shared__ __bf16 As[RB * 64];
    __shared__ __bf16 Bs[256 * 64];
    __shared__ float ssLDS[4][RB];
    __shared__ float invLDS[RB];

    const int tid = threadIdx.x;
    const int row0 = blockIdx.x * RB;
    const int lane = tid & 63;
    const int w = tid >> 6;
    const int rl = lane & 15;
    const int g = lane >> 4;
    const int rg = tid >> 7, kc8 = (tid >> 4) & 7, lo = tid & 15;
    const int grow = row0 + rg * 16 + lo;

    // B prologue (k0 = 0)
    float4 rb0[8], rb1[8];
#pragma unroll
    for (int s = 0; s < 8; ++s) {
        int i = tid + s * 256;
        int cg = i >> 7, kc = (i >> 4) & 7, blo = i & 15;
        const float* p = W1 + (size_t)(cg * 16 + blo) * K2 + kc * 8;
        rb0[s] = *(const float4*)p;
        rb1[s] = *(const float4*)(p + 4);
    }

    f32x4 acc[2][4];
#pragma unroll
    for (int rf = 0; rf < 2; ++rf)
#pragma unroll
        for (int nf = 0; nf < 4; ++nf) acc[rf][nf] = (f32x4){0.f, 0.f, 0.f, 0.f};

    for (int k0 = 0; k0 < K2; k0 += 64) {
        // fused A-staging (build X1 tile on the fly)
        bf16x8 av;
        if (k0 < 256) {
            av = *(const bf16x8*)(h1 + (size_t)grow * D + k0 + kc8 * 8);
        } else {
            float f[8];
#pragma unroll
            for (int e = 0; e < 8; ++e) f[e] = 0.f;
            const __bf16* base = h1 + (size_t)(BATCH + grow * S1) * D + (k0 - 256) + kc8 * 8;
#pragma unroll
            for (int j = 0; j < S1; ++j) {
                bf16x8 vv = *(const bf16x8*)(base + (size_t)j * D);
#pragma unroll
                for (int e = 0; e < 8; ++e) f[e] += (float)vv[e];
            }
#pragma unroll
            for (int e = 0; e < 8; ++e) av[e] = (__bf16)(f[e] * 0.1f);
        }
        *(bf16x8*)(As + (size_t)tid * 8) = av;
        // B-staging from prefetched regs with cvt
#pragma unroll
        for (int s = 0; s < 8; ++s) {
            int i = tid + s * 256;
            bf16x8 bb;
            bb[0] = (__bf16)rb0[s].x; bb[1] = (__bf16)rb0[s].y;
            bb[2] = (__bf16)rb0[s].z; bb[3] = (__bf16)rb0[s].w;
            bb[4] = (__bf16)rb1[s].x; bb[5] = (__bf16)rb1[s].y;
            bb[6] = (__bf16)rb1[s].z; bb[7] = (__bf16)rb1[s].w;
            *(bf16x8*)(Bs + (size_t)i * 8) = bb;
        }
        __syncthreads();
        if (k0 + 64 < K2) {
#pragma unroll
            for (int s = 0; s < 8; ++s) {
                int i = tid + s * 256;
                int cg = i >> 7, kc = (i >> 4) & 7, blo = i & 15;
                const float* p = W1 + (size_t)(cg * 16 + blo) * K2 + (k0 + 64) + kc * 8;
                rb0[s] = *(const float4*)p;
                rb1[s] = *(const float4*)(p + 4);
            }
        }
#pragma unroll
        for (int kf = 0; kf < 2; ++kf) {
            const int kc = kf * 4 + g;
            bf16x8 af[2], bfr[4];
#pragma unroll
            for (int rf = 0; rf < 2; ++rf)
                af[rf] = *(const bf16x8*)(As + ((size_t)(rf * 8 + kc) * 16 + rl) * 8);
#pragma unroll
            for (int nf = 0; nf < 4; ++nf)
                bfr[nf] = *(const bf16x8*)(Bs + ((size_t)((w * 4 + nf) * 8 + kc) * 16 + rl) * 8);
#pragma unroll
            for (int rf = 0; rf < 2; ++rf)
#pragma unroll
                for (int nf = 0; nf < 4; ++nf)
                    acc[rf][nf] = __builtin_amdgcn_mfma_f32_16x16x32_bf16(
                        af[rf], bfr[nf], acc[rf][nf], 0, 0, 0);
        }
        __syncthreads();
    }

    float bv[4];
#pragma unroll
    for (int nf = 0; nf < 4; ++nf) bv[nf] = b1[w * 64 + nf * 16 + rl];

#pragma unroll
    for (int rf = 0; rf < 2; ++rf) {
        float ss0 = 0.f, ss1 = 0.f, ss2 = 0.f, ss3 = 0.f;
#pragma unroll
        for (int nf = 0; nf < 4; ++nf) {
            float v0 = fmaxf(acc[rf][nf][0] + bv[nf], 0.f);
            float v1 = fmaxf(acc[rf][nf][1] + bv[nf], 0.f);
            float v2 = fmaxf(acc[rf][nf][2] + bv[nf], 0.f);
            float v3 = fmaxf(acc[rf][nf][3] + bv[nf], 0.f);
            acc[rf][nf][0] = v0; acc[rf][nf][1] = v1;
            acc[rf][nf][2] = v2; acc[rf][nf][3] = v3;
            ss0 += v0 * v0; ss1 += v1 * v1; ss2 += v2 * v2; ss3 += v3 * v3;
        }
#pragma unroll
        for (int m = 1; m < 16; m <<= 1) {
            ss0 += __shfl_xor(ss0, m);
            ss1 += __shfl_xor(ss1, m);
            ss2 += __shfl_xor(ss2, m);
            ss3 += __shfl_xor(ss3, m);
        }
        float ssv = (rl == 0) ? ss0 : (rl == 1) ? ss1 : (rl == 2) ? ss2 : ss3;
        if (rl < 4) ssLDS[w][rf * 16 + g * 4 + rl] = ssv;
    }
    __syncthreads();
    if (tid < RB) {
        float t = ssLDS[0][tid] + ssLDS[1][tid] + ssLDS[2][tid] + ssLDS[3][tid];
        invLDS[tid] = (t > 0.f) ? rsqrtf(t) : 1.0f;
    }
    __syncthreads();
#pragma unroll
    for (int rf = 0; rf < 2; ++rf)
#pragma unroll
        for (int j = 0; j < 4; ++j) {
            const int row = rf * 16 + g * 4 + j;
            const float inv = invLDS[row];
#pragma unroll
            for (int nf = 0; nf < 4; ++nf)
                Out[(size_t)(row0 + row) * D + w * 64 + nf * 16 + rl] = acc[rf][nf][j] * inv;
        }
}

// ---------------------------------------------------------------------------
extern "C" void kernel_launch(void* const* d_in, const int* in_sizes, int n_in,
                              void* d_out, int out_size, void* d_ws, size_t ws_size,
                              hipStream_t stream) {
    const float* features = (const float*)d_in[0];
    const float* W0       = (const float*)d_in[1];
    const float* b0       = (const float*)d_in[2];
    const float* W1       = (const float*)d_in[3];
    const float* b1       = (const float*)d_in[4];
    const int*   nodes2   = (const int*)d_in[5];
    const int*   neigh2   = (const int*)d_in[6];
    const int*   neigh1   = (const int*)d_in[7];
    float* out = (float*)d_out;

    __bf16* h1b = (__bf16*)d_ws;   // 11264*256*2 = 5.75 MB

    fused_layer0<<<N1 / 32, 256, 0, stream>>>(features, W0, b0, nodes2, neigh2,
                                              neigh1, h1b);
    fused_layer1<<<BATCH / 32, 256, 0, stream>>>(h1b, W1, b1, out);
}